// Round 8
// baseline (156.796 us; speedup 1.0000x reference)
//
#include <hip/hip_runtime.h>
#include <math.h>

#define Bn 4
#define Nn 512
#define Dn 64
#define Hn 8
#define TR 64          // rows per tile-block
#define NT (Nn / TR)   // 8 tiles per (b,q)
#define PS 68          // p/g row stride (words): banks 4h+c, distinct per head
#define PART 80        // partial floats per block: 64 PV + 8 expsum + 8 gsum

// ---------------- Kernel 1: QKV projection -------------------------------
__global__ __launch_bounds__(64) void qkv_kernel(
    const float* __restrict__ nin, const float* __restrict__ Wq,
    const float* __restrict__ Wk, const float* __restrict__ Wv,
    float* __restrict__ Qw, float* __restrict__ Kw, float* __restrict__ Vw)
{
    const int row = blockIdx.x;   // 0 .. B*N-1
    const int d = threadIdx.x;    // 0 .. 63
    __shared__ float nrow[Dn];
    nrow[d] = nin[row * Dn + d];
    __syncthreads();
    float aq = 0.f, ak = 0.f, av = 0.f;
#pragma unroll
    for (int k = 0; k < Dn; ++k) {
        const float nv = nrow[k];
        aq = fmaf(nv, Wq[k * Dn + d], aq);
        ak = fmaf(nv, Wk[k * Dn + d], ak);
        av = fmaf(nv, Wv[k * Dn + d], av);
    }
    Qw[row * Dn + d] = aq;
    Kw[row * Dn + d] = ak;
    Vw[row * Dn + d] = av;
}

// ---------------- Kernel 2: streaming tile kernel -------------------------
// One block per (b,q,tile). Lane = (row r, d-quarter dq): quad owns a row.
// e/K/Q segments load straight to registers (one 64B line per lane - no LDS
// staging). eb/gg 8-head partials per 16-float segment, quad-reduced via DPP
// shuffles; A local for heads {2dq,2dq+1}, quad-gathered to all 8. e_out
// segment computed from registers + Oe LDS broadcast, stored cached (each
// line produced whole by one lane -> L2 merge). LDS only holds weights and
// p/g rows (11.8KB). PV phase reads only the wave's own rows -> no barrier.
__global__ __launch_bounds__(256, 6) void stream_kernel(
    const float* __restrict__ e,
    const float* __restrict__ Qw, const float* __restrict__ Kw,
    const float* __restrict__ Vw,
    const float* __restrict__ WeG, const float* __restrict__ WgG,
    const float* __restrict__ OeG,
    float* __restrict__ eout, float* __restrict__ part)
{
    const int bid  = blockIdx.x;        // bq*NT + tile
    const int bq   = bid >> 3;          // NT = 8
    const int tile = bid & 7;
    const int b    = bq >> 9;           // N = 512
    const int m0   = tile * TR;
    const int t    = threadIdx.x;       // 0..255
    const int w    = t >> 6;            // wave 0..3: rows w*16..w*16+15
    const int l    = t & 63;
    const int r    = l >> 2;            // row within wave strip
    const int dq   = l & 3;             // d-quarter (16 floats = 1 line)
    const int row  = w * 16 + r;        // row within tile
    const int m    = m0 + row;          // global m

    __shared__ __align__(16) float we_s[Hn][Dn];    // 2048 B
    __shared__ __align__(16) float wg_s[Hn][Dn];    // 2048 B
    __shared__ __align__(16) float oe_s[Hn][Dn];    // 2048 B
    __shared__ float ps_s[Hn][PS];                  // 2176 B  p = exp(ehat)
    __shared__ float gs_s[Hn][PS];                  // 2176 B  sigmoid(gg)
    __shared__ float accb[4][Dn];                   // 1024 B
    __shared__ float smb[4][Hn];                    // 128 B
    __shared__ float gsb[4][Hn];                    // 128 B

    // 1) e segment -> regs: this lane's own 64B line, 4 back-to-back float4
    const float4* ep = (const float4*)(e + ((size_t)bq * Nn + m) * Dn + dq * 16);
    float4 ev[4];
#pragma unroll
    for (int j = 0; j < 4; ++j) ev[j] = ep[j];

    // 2) K/Q segments (L2-hot); lane's d-range = heads {2dq, 2dq+1} exactly
    const float4* kp = (const float4*)(Kw + ((size_t)b * Nn + m) * Dn + dq * 16);
    const float4 k0 = kp[0], k1 = kp[1], k2 = kp[2], k3 = kp[3];
    const float4* qp = (const float4*)(Qw + (size_t)bq * Dn + dq * 16);
    const float4 q0 = qp[0], q1 = qp[1], q2 = qp[2], q3 = qp[3];

    // 3) weights staging (L2-hot). We/Wg (D,H) -> [h][d]; Oe (H,D) copy.
    for (int i = t; i < Dn * Hn; i += 256) {
        const int d = i >> 3, h = i & 7;
        we_s[h][d] = WeG[i];
        wg_s[h][d] = WgG[i];
        ((float*)oe_s)[i] = OeG[i];
    }

    // 4) A for own heads (local 8-float dots), clipped
    const float qscale = 0.35355339059327373f;  // 1/sqrt(8)
    float a0 = k0.x*q0.x + k0.y*q0.y + k0.z*q0.z + k0.w*q0.w
             + k1.x*q1.x + k1.y*q1.y + k1.z*q1.z + k1.w*q1.w;
    float a1 = k2.x*q2.x + k2.y*q2.y + k2.z*q2.z + k2.w*q2.w
             + k3.x*q3.x + k3.y*q3.y + k3.z*q3.z + k3.w*q3.w;
    a0 = fminf(fmaxf(a0 * qscale, -5.f), 5.f);
    a1 = fminf(fmaxf(a1 * qscale, -5.f), 5.f);

    __syncthreads();   // weights visible

    // 5) eb/gg 8-head partials over this lane's 16 e-floats
    float ebp[Hn], ggp[Hn];
#pragma unroll
    for (int h = 0; h < Hn; ++h) { ebp[h] = 0.f; ggp[h] = 0.f; }
#pragma unroll
    for (int j = 0; j < 4; ++j) {
        const float4 e4 = ev[j];
#pragma unroll
        for (int h = 0; h < Hn; ++h) {
            const float4 wv = *(const float4*)&we_s[h][dq * 16 + j * 4];
            const float4 gv = *(const float4*)&wg_s[h][dq * 16 + j * 4];
            ebp[h] = fmaf(e4.x, wv.x, fmaf(e4.y, wv.y,
                      fmaf(e4.z, wv.z, fmaf(e4.w, wv.w, ebp[h]))));
            ggp[h] = fmaf(e4.x, gv.x, fmaf(e4.y, gv.y,
                      fmaf(e4.z, gv.z, fmaf(e4.w, gv.w, ggp[h]))));
        }
    }

    // 6) quad-reduce partials (xor 1,2 = DPP quad_perm, VALU pipe)
#pragma unroll
    for (int h = 0; h < Hn; ++h) {
        ebp[h] += __shfl_xor(ebp[h], 1, 64);
        ebp[h] += __shfl_xor(ebp[h], 2, 64);
        ggp[h] += __shfl_xor(ggp[h], 1, 64);
        ggp[h] += __shfl_xor(ggp[h], 2, 64);
    }

    // 7) quad-gather A to all 8 heads (verified mapping for dq=0..3)
    const float n0 = __shfl_xor(a0, 1, 64);
    const float n1 = __shfl_xor(a1, 1, 64);
    const bool odd = dq & 1, hi = dq & 2;
    const float h40 = odd ? n0 : a0, h41 = odd ? n1 : a1;
    const float h42 = odd ? a0 : n0, h43 = odd ? a1 : n1;
    const float g0 = __shfl_xor(h40, 2, 64), g1 = __shfl_xor(h41, 2, 64);
    const float g2 = __shfl_xor(h42, 2, 64), g3 = __shfl_xor(h43, 2, 64);
    float eh[Hn];
    eh[0] = (hi ? g0 : h40) + ebp[0];
    eh[1] = (hi ? g1 : h41) + ebp[1];
    eh[2] = (hi ? g2 : h42) + ebp[2];
    eh[3] = (hi ? g3 : h43) + ebp[3];
    eh[4] = (hi ? h40 : g0) + ebp[4];
    eh[5] = (hi ? h41 : g1) + ebp[5];
    eh[6] = (hi ? h42 : g2) + ebp[6];
    eh[7] = (hi ? h43 : g3) + ebp[7];

    // 8) own-head p = exp(ehat), g = sigmoid(gg) -> LDS (one writer per slot)
    {
        const float eo0 = hi ? (odd ? eh[6] : eh[4]) : (odd ? eh[2] : eh[0]);
        const float eo1 = hi ? (odd ? eh[7] : eh[5]) : (odd ? eh[3] : eh[1]);
        const float go0 = hi ? (odd ? ggp[6] : ggp[4]) : (odd ? ggp[2] : ggp[0]);
        const float go1 = hi ? (odd ? ggp[7] : ggp[5]) : (odd ? ggp[3] : ggp[1]);
        ps_s[2 * dq][row]     = __expf(eo0);
        ps_s[2 * dq + 1][row] = __expf(eo1);
        gs_s[2 * dq][row]     = 1.f / (1.f + __expf(-go0));
        gs_s[2 * dq + 1][row] = 1.f / (1.f + __expf(-go1));
    }

    // 9) e_out segment: lane produces its own full 64B line, cached stores
    {
        float4* eo = (float4*)(eout + ((size_t)bq * Nn + m) * Dn + dq * 16);
#pragma unroll
        for (int j = 0; j < 4; ++j) {
            float4 o; o.x = o.y = o.z = o.w = 0.f;
#pragma unroll
            for (int h = 0; h < Hn; ++h) {
                const float4 w4 = *(const float4*)&oe_s[h][dq * 16 + j * 4];
                o.x = fmaf(eh[h], w4.x, o.x);
                o.y = fmaf(eh[h], w4.y, o.y);
                o.z = fmaf(eh[h], w4.z, o.z);
                o.w = fmaf(eh[h], w4.w, o.w);
            }
            eo[j] = o;
        }
    }

    // 10) PV + exp/gate sums over this wave's own rows (no barrier needed:
    //     ps/gs rows w*16..w*16+15 were written by this same wave)
    const int hc = l >> 3;
    float sm = 0.f, gsum = 0.f, acc = 0.f;
    const float* vb = Vw + ((size_t)b * Nn + m0 + w * 16) * Dn;
#pragma unroll
    for (int i = 0; i < 16; ++i) {
        const float p = ps_s[hc][w * 16 + i];
        sm += p;
        gsum += gs_s[hc][w * 16 + i];
        acc = fmaf(p, vb[i * Dn + l], acc);
    }
    accb[w][l] = acc;
    if ((l & 7) == 0) { smb[w][hc] = sm; gsb[w][hc] = gsum; }
    __syncthreads();

    // 11) fold 4 waves, emit 80-float partial
    if (w == 0) {
        const float O = accb[0][l] + accb[1][l] + accb[2][l] + accb[3][l];
        float* pb = part + (size_t)bid * PART;
        pb[l] = O;
        if (l < 8) {
            pb[64 + l] = smb[0][l] + smb[1][l] + smb[2][l] + smb[3][l];
            pb[72 + l] = gsb[0][l] + gsb[1][l] + gsb[2][l] + gsb[3][l];
        }
    }
}

// ---------------- Kernel 3: fold partials -> n_out ------------------------
__global__ __launch_bounds__(64) void reduce_kernel(
    const float* __restrict__ part, const float* __restrict__ WoG,
    float* __restrict__ nout)
{
    const int bq = blockIdx.x;
    const int l  = threadIdx.x;
    const int h  = l >> 3;
    const float* pb = part + (size_t)bq * NT * PART;
    float O = 0.f, S = 0.f, G = 0.f;
#pragma unroll
    for (int tl = 0; tl < NT; ++tl) {
        O += pb[tl * PART + l];
        S += pb[tl * PART + 64 + h];
        G += pb[tl * PART + 72 + h];
    }
    __shared__ float vo_s[Dn];
    vo_s[l] = (O / S) * log1pf(G);
    __syncthreads();
    float a = 0.f;
#pragma unroll
    for (int k = 0; k < Dn; ++k)
        a = fmaf(vo_s[k], WoG[k * Dn + l], a);
    nout[(size_t)bq * Dn + l] = a;
}

// ---------------- Host launcher -------------------------------------------
extern "C" void kernel_launch(void* const* d_in, const int* in_sizes, int n_in,
                              void* d_out, int out_size, void* d_ws, size_t ws_size,
                              hipStream_t stream)
{
    (void)in_sizes; (void)n_in; (void)out_size; (void)ws_size;
    const float* nin = (const float*)d_in[0];
    const float* e   = (const float*)d_in[1];
    const float* Wq  = (const float*)d_in[2];
    const float* Wk  = (const float*)d_in[3];
    const float* Wv  = (const float*)d_in[4];
    const float* Wo  = (const float*)d_in[5];
    const float* Wg  = (const float*)d_in[6];
    const float* We  = (const float*)d_in[7];
    const float* Oe  = (const float*)d_in[8];

    float* Qw   = (float*)d_ws;               // B*N*D floats
    float* Kw   = Qw + Bn * Nn * Dn;
    float* Vw   = Kw + Bn * Nn * Dn;
    float* part = Vw + Bn * Nn * Dn;          // B*N*NT*PART floats (5.2 MB)

    float* nout = (float*)d_out;              // B*N*D floats
    float* eout = nout + Bn * Nn * Dn;        // B*N*N*D floats

    qkv_kernel<<<Bn * Nn, 64, 0, stream>>>(nin, Wq, Wk, Wv, Qw, Kw, Vw);
    stream_kernel<<<Bn * Nn * NT, 256, 0, stream>>>(e, Qw, Kw, Vw, We, Wg, Oe,
                                                    eout, part);
    reduce_kernel<<<Bn * Nn, 64, 0, stream>>>(part, Wo, nout);
}